// Round 4
// baseline (312.318 us; speedup 1.0000x reference)
//
#include <hip/hip_runtime.h>

typedef _Float16 half8 __attribute__((ext_vector_type(8)));
typedef _Float16 half4 __attribute__((ext_vector_type(4)));
typedef _Float16 half2v __attribute__((ext_vector_type(2)));
typedef float f32x4 __attribute__((ext_vector_type(4)));

#define TT 512
#define HH 64
#define MB 8      // real batches per block -> 256 blocks (cols 8..15 garbage-contained)
#define S  104    // state row stride (f16): [h(64)|x(4)|1|zeros|pad]

__device__ __forceinline__ float sigm(float x) {
    return __builtin_amdgcn_rcpf(1.f + __builtin_amdgcn_exp2f(-1.4426950408889634f * x));
}
__device__ __forceinline__ float tanh_f(float x) {
    return 1.f - 2.f * __builtin_amdgcn_rcpf(1.f + __builtin_amdgcn_exp2f(2.8853900817779268f * x));
}

__global__ __launch_bounds__(512, 1)
void lstm_v4(const float* __restrict__ x,
             const float* __restrict__ W_ih,
             const float* __restrict__ W_hh,
             const float* __restrict__ b_ih,
             const float* __restrict__ b_hh,
             const float* __restrict__ W_fc,
             const float* __restrict__ b_fc,
             float* __restrict__ out)
{
    __shared__ __align__(16) _Float16 st[2][16 * S];

    const int tid = threadIdx.x;
    const int w   = tid >> 6;      // wave 0..7
    const int l   = tid & 63;
    const int q   = l >> 4;
    const int col = l & 15;
    const int b0  = blockIdx.x * MB;

    // ---- persistent A fragments (weights), 2 tiles per wave ----
    // tile p of wave w covers gate-rows r(m) = 64*(m&3) + 8w + 2*(m>>2) + p
    // => lane (q,col) reg j = gate j of unit u = 8w + 2q + p  (adjacent for p=0,1)
    half8 aw[2][3];
    #pragma unroll
    for (int p = 0; p < 2; ++p) {
        const int r = 64 * (col & 3) + 8 * w + 2 * (col >> 2) + p;
        #pragma unroll
        for (int c = 0; c < 2; ++c) {
            const float* src = W_hh + r * HH + 32 * c + 8 * q;
            half8 v;
            #pragma unroll
            for (int j = 0; j < 8; ++j) v[j] = (_Float16)src[j];
            aw[p][c] = v;
        }
        half8 v;
        #pragma unroll
        for (int j = 0; j < 8; ++j) v[j] = (_Float16)0.f;
        if (q == 0) {   // k=64..67 -> W_ih, k=68 -> bias
            #pragma unroll
            for (int j = 0; j < 4; ++j) v[j] = (_Float16)W_ih[r * 4 + j];
            v[4] = (_Float16)(b_ih[r] + b_hh[r]);
        }
        aw[p][2] = v;
    }

    // ---- init LDS ----
    {
        _Float16* p0 = &st[0][0];
        for (int i = tid; i < 2 * 16 * S; i += 512) p0[i] = (_Float16)0.f;
    }
    __syncthreads();
    if (tid < 32) st[tid >> 4][(tid & 15) * S + 68] = (_Float16)1.0f;

    float4 xnext;
    if (tid < MB) {
        const float4* xb = (const float4*)(x + (size_t)(b0 + tid) * TT * 4);
        float4 x0 = xb[0];
        _Float16* d = &st[0][tid * S + 64];
        half4 hx;
        hx[0] = (_Float16)x0.x; hx[1] = (_Float16)x0.y;
        hx[2] = (_Float16)x0.z; hx[3] = (_Float16)x0.w;
        *(half4*)d = hx;
        xnext = xb[1];
    }
    __syncthreads();

    float cst[2] = {0.f, 0.f};

    #pragma unroll 2
    for (int t = 0; t < TT; ++t) {
        const int rb = t & 1, wb = rb ^ 1;
        const _Float16* sr = &st[rb][0];

        // B fragments: B[k=8q+j][n=col] = state[col][k]
        half8 bh0 = *(const half8*)&sr[col * S +      8 * q];   // k 0..31
        half8 bh1 = *(const half8*)&sr[col * S + 32 + 8 * q];   // k 32..63
        // x/bias chunk: all quads read the SAME 16B (broadcast); lanes q>0
        // feed k-slots 72..95 whose A is zero -> don't-care
        half8 bx  = *(const half8*)&sr[col * S + 64];

        // write x_{t+1}; prefetch x_{t+2}
        if (tid < MB) {
            _Float16* d = &st[wb][tid * S + 64];
            half4 hx;
            hx[0] = (_Float16)xnext.x; hx[1] = (_Float16)xnext.y;
            hx[2] = (_Float16)xnext.z; hx[3] = (_Float16)xnext.w;
            *(half4*)d = hx;
            const int tn = (t + 2 < TT) ? (t + 2) : (TT - 1);
            xnext = *(const float4*)(x + ((size_t)(b0 + tid) * TT + tn) * 4);
        }

        // 6 INDEPENDENT MFMAs (zero-init), then tree-add: dep depth 1 mfma + 2 adds
        const f32x4 z = {0.f, 0.f, 0.f, 0.f};
        f32x4 t00 = __builtin_amdgcn_mfma_f32_16x16x32_f16(aw[0][0], bh0, z, 0, 0, 0);
        f32x4 t01 = __builtin_amdgcn_mfma_f32_16x16x32_f16(aw[0][1], bh1, z, 0, 0, 0);
        f32x4 t0x = __builtin_amdgcn_mfma_f32_16x16x32_f16(aw[0][2], bx,  z, 0, 0, 0);
        f32x4 t10 = __builtin_amdgcn_mfma_f32_16x16x32_f16(aw[1][0], bh0, z, 0, 0, 0);
        f32x4 t11 = __builtin_amdgcn_mfma_f32_16x16x32_f16(aw[1][1], bh1, z, 0, 0, 0);
        f32x4 t1x = __builtin_amdgcn_mfma_f32_16x16x32_f16(aw[1][2], bx,  z, 0, 0, 0);
        f32x4 acc0 = (t00 + t01) + t0x;
        f32x4 acc1 = (t10 + t11) + t1x;

        // cell update: 2 cells/lane (units u=8w+2q+p), ILP across p; packed b32 h-write
        _Float16* sw = &st[wb][0];
        {
            const float gi0 = acc0[0], gf0 = acc0[1], gg0 = acc0[2], go0 = acc0[3];
            const float gi1 = acc1[0], gf1 = acc1[1], gg1 = acc1[2], go1 = acc1[3];
            float c0 = sigm(gf0) * cst[0] + sigm(gi0) * tanh_f(gg0);
            float c1 = sigm(gf1) * cst[1] + sigm(gi1) * tanh_f(gg1);
            cst[0] = c0; cst[1] = c1;
            half2v hv;
            hv[0] = (_Float16)(sigm(go0) * tanh_f(c0));
            hv[1] = (_Float16)(sigm(go1) * tanh_f(c1));
            *(half2v*)&sw[col * S + 8 * w + 2 * q] = hv;   // 4B aligned, 2-way banks: free
        }
        __syncthreads();
    }

    // ---- FC epilogue: final h in st[0] (TT even) ----
    if (tid < MB * 4) {
        const int b = tid >> 2, o = tid & 3;
        float s = b_fc[o];
        const float* wf = W_fc + o * HH;
        #pragma unroll
        for (int k = 0; k < HH; ++k)
            s = fmaf((float)st[0][b * S + k], wf[k], s);
        out[(size_t)(b0 + b) * 4 + o] = s;
    }
}

extern "C" void kernel_launch(void* const* d_in, const int* in_sizes, int n_in,
                              void* d_out, int out_size, void* d_ws, size_t ws_size,
                              hipStream_t stream) {
    const float* x    = (const float*)d_in[0];
    const float* W_ih = (const float*)d_in[1];
    const float* W_hh = (const float*)d_in[2];
    const float* b_ih = (const float*)d_in[3];
    const float* b_hh = (const float*)d_in[4];
    const float* W_fc = (const float*)d_in[5];
    const float* b_fc = (const float*)d_in[6];
    float* out = (float*)d_out;
    lstm_v4<<<2048 / MB, 512, 0, stream>>>(x, W_ih, W_hh, b_ih, b_hh, W_fc, b_fc, out);
}